// Round 12
// baseline (288.710 us; speedup 1.0000x reference)
//
#include <hip/hip_runtime.h>

#define B_ 16
#define K_ 20
#define H_ 256
#define W_ 256
#define HW_ (H_*W_)
#define BK_ (B_*K_)
#define TH_ 8           // rows per strip (32 strips/image)
#define KT_ 10          // classes per k-half (fused) and per stats block
#define SCH_ 16         // stats row-chunks
#define NSTR_ 32
#define NBLK_FUSED_ (B_*NSTR_*2)   // 1024 blocks

// ws layout (floats): statsP [SCH_][4][BK_] | nd [K_][2] (atomic) | cnt
#define WS_ND_   (SCH_*4*BK_)      // 20480
#define WS_CNT_  (WS_ND_ + 2*K_)   // 20520

// Gaussian taps exp(-d^2/50), d=1..4 (symmetric: 4 distinct + center 1.0)
#define G1T 0.980198673f
#define G2T 0.923116346f
#define G3T 0.835270211f
#define G4T 0.726149037f

__device__ __forceinline__ float rfl(float v) {   // force value into SGPR
    return __int_as_float(__builtin_amdgcn_readfirstlane(__float_as_int(v)));
}

// ---------------------------------------------------------------------------
// stats_k: per-(b,k) sums of labels and labels*inputs_c as per-chunk partials
// (KT=10, validated R11). Also zeroes the nd accumulators + completion cnt.
// ---------------------------------------------------------------------------
__global__ __launch_bounds__(256) void stats_k(const float* __restrict__ labels,
                                               const float* __restrict__ inputs,
                                               float* __restrict__ ws) {
    const int x = threadIdx.x;
    const int chunk = blockIdx.x;
    const int kt = blockIdx.y;          // 0..1
    const int b  = blockIdx.z;
    const int k0 = kt * KT_;
    if (chunk == 0 && kt == 0 && b == 0 && x < 2*K_ + 1)
        ws[WS_ND_ + x] = 0.f;           // nd[40] + cnt (bit pattern 0)

    const int cbase = chunk * (16 * W_ / 4);
    const float4* in0 = (const float4*)inputs + (size_t)b * 3 * (HW_/4) + cbase;
    const float4* in1 = in0 + (HW_/4);
    const float4* in2 = in1 + (HW_/4);
    const float4* lb  = (const float4*)labels + (size_t)(b * K_ + k0) * (HW_/4) + cbase;

    float acc[KT_][4];
#pragma unroll
    for (int kk = 0; kk < KT_; ++kk)
        acc[kk][0] = acc[kk][1] = acc[kk][2] = acc[kk][3] = 0.f;

#pragma unroll
    for (int it = 0; it < 4; ++it) {
        const int idx = it * 256 + x;
        const float4 a0 = in0[idx];
        const float4 a1 = in1[idx];
        const float4 a2 = in2[idx];
#pragma unroll
        for (int kk = 0; kk < KT_; ++kk) {
            const float4 l = lb[kk * (HW_/4) + idx];
            acc[kk][0] += (l.x + l.y) + (l.z + l.w);
            acc[kk][1] += fmaf(l.w, a0.w, fmaf(l.z, a0.z, fmaf(l.y, a0.y, l.x * a0.x)));
            acc[kk][2] += fmaf(l.w, a1.w, fmaf(l.z, a1.z, fmaf(l.y, a1.y, l.x * a1.x)));
            acc[kk][3] += fmaf(l.w, a2.w, fmaf(l.z, a2.z, fmaf(l.y, a2.y, l.x * a2.x)));
        }
    }

#pragma unroll
    for (int kk = 0; kk < KT_; ++kk)
#pragma unroll
        for (int q = 0; q < 4; ++q)
            for (int o = 32; o > 0; o >>= 1)
                acc[kk][q] += __shfl_down(acc[kk][q], o);

    __shared__ float sred[4][KT_][4];
    const int widx = x >> 6, lane = x & 63;
    if (lane == 0)
#pragma unroll
        for (int kk = 0; kk < KT_; ++kk)
#pragma unroll
            for (int q = 0; q < 4; ++q) sred[widx][kk][q] = acc[kk][q];
    __syncthreads();
    if (x < KT_ * 4) {
        const int kk = x >> 2, q = x & 3;
        const float v = sred[0][kk][q] + sred[1][kk][q] + sred[2][kk][q] + sred[3][kk][q];
        ws[(chunk * 4 + q) * BK_ + b * K_ + k0 + kk] = v;
    }
}

// ---------------------------------------------------------------------------
// fused_k, K-INNER adjoint form. Block = (b, 8-row strip, k-half of 10).
// Inputs staged ONCE into LDS as float4(a0,a1,a2,x2) -> the 20x global
// re-read of inputs (284 MB logical, the dominant per-CU cache-path stream)
// becomes LDS traffic (proven non-binding). Per k: 16 label rows in a flat
// register array (static indices), v-blur->LDS float2 pairs (R11), RAW
// barrier (lgkm-only drain, R8), h-blur + weight + combine, per-k block
// partial via 2 atomicAdds, next-k labels prefetched across the barriers.
//   num_k = sum (l_k*w_k)*blur(l_k),  den_k = sum w_k*blur(l_k)
// grid: 1024 blocks 1D, bijective XCD-chunk swizzle (1024 % 8 == 0).
// LDS 41.3 KB -> 3 blocks/CU.
// ---------------------------------------------------------------------------
__global__ __launch_bounds__(256) void fused_k(const float* __restrict__ labels,
                                               const float* __restrict__ inputs,
                                               float* __restrict__ ws,
                                               float* __restrict__ out) {
    const int x = threadIdx.x;            // column
    const int lane = x & 63, widx = x >> 6;
    const int bid = blockIdx.x;
    const int swz = (bid & 7) * (NBLK_FUSED_ / 8) + (bid >> 3);
    const int b   = swz >> 6;             // 16 images
    const int rem = swz & 63;
    const int sg  = rem >> 1;             // 32 strips
    const int kh  = rem & 1;              // k-half
    const int r0  = sg * TH_;
    const int k0g = kh * KT_;

    const float* i0p = inputs + (size_t)b * 3 * HW_;
    const float* i1p = i0p + HW_;
    const float* i2p = i1p + HW_;

    __shared__ float4 si[TH_][W_];        // (a0,a1,a2,x2) per px: 32 KB
    __shared__ float2 sv[TH_/2][W_ + 8];  // v-blur row pairs: 8.4 KB
    __shared__ float rb[2][4][2];
    __shared__ unsigned sdone;

    if (x < 32) {                         // zero sv pads: 4 pairs x 8 cols
        const int j2 = x >> 3, p = x & 7;
        const int col = (p < 4) ? p : (W_ + p);
        sv[j2][col] = make_float2(0.f, 0.f);
    }

    // ---- stage inputs for the strip's output rows (once per block) ----
#pragma unroll
    for (int j = 0; j < TH_; ++j) {
        const int r = r0 + j;
        const float a0 = i0p[r * W_ + x], a1 = i1p[r * W_ + x], a2 = i2p[r * W_ + x];
        si[j][x] = make_float4(a0, a1, a2, fmaf(a0, a0, fmaf(a1, a1, a2 * a2)));
    }

    // ---- first-k labels: rows r0-4 .. r0+11 (flat array, static indices) ----
    const float* lb = labels + (size_t)(b * K_ + k0g) * HW_;
    float L[16], NL[16];
#pragma unroll
    for (int i = 0; i < 16; ++i) {
        const int gr = r0 - 4 + i;
        L[i] = (gr >= 0 && gr < H_) ? lb[gr * W_ + x] : 0.f;
    }

    __syncthreads();                      // staging + pads visible (full, once)

#pragma unroll 1
    for (int kk = 0; kk < KT_; ++kk) {
        const int bk = b * K_ + k0g + kk;
        // ---- class mean from stats partials (scalar path, uniform) ----
        float s0 = 0.f, s1 = 0.f, s2 = 0.f, s3 = 0.f;
#pragma unroll
        for (int c = 0; c < SCH_; ++c) {
            const float* p = ws + c * 4 * BK_;
            s0 += p[bk]; s1 += p[BK_ + bk]; s2 += p[2*BK_ + bk]; s3 += p[3*BK_ + bk];
        }
        const float dnv = s0 + 1e-5f * (float)HW_;
        const float c0 = s1 / dnv, c1 = s2 / dnv, c2 = s3 / dnv;
        const float tc0 = rfl(2.f * c0), tc1 = rfl(2.f * c1), tc2 = rfl(2.f * c2);
        const float m2v = rfl(c0*c0 + c1*c1 + c2*c2);

        // ---- 1. prefetch next-k labels (in flight across both barriers) ----
        if (kk < KT_ - 1) {
#pragma unroll
            for (int i = 0; i < 16; ++i) {
                const int gr = r0 - 4 + i;
                NL[i] = (gr >= 0 && gr < H_) ? lb[HW_ + gr * W_ + x] : 0.f;
            }
        }
        // ---- 2. vertical 9-tap, row pairs -> LDS ----
#pragma unroll
        for (int j2 = 0; j2 < TH_/2; ++j2) {
            const int j = 2 * j2;
            const float v0 = fmaf(G4T, L[j]   + L[j+8],
                             fmaf(G3T, L[j+1] + L[j+7],
                             fmaf(G2T, L[j+2] + L[j+6],
                             fmaf(G1T, L[j+3] + L[j+5], L[j+4]))));
            const float v1 = fmaf(G4T, L[j+1] + L[j+9],
                             fmaf(G3T, L[j+2] + L[j+8],
                             fmaf(G2T, L[j+3] + L[j+7],
                             fmaf(G1T, L[j+4] + L[j+6], L[j+5]))));
            sv[j2][4 + x] = make_float2(v0, v1);
        }
        // ---- 3. RAW barrier: drain LDS only; label prefetch stays in flight --
        asm volatile("s_waitcnt lgkmcnt(0)" ::: "memory");
        __builtin_amdgcn_s_barrier();
        asm volatile("" ::: "memory");
        // ---- 4. h-blur + weight (inputs from LDS) + combine ----
        float num = 0.f, den = 0.f;
#pragma unroll
        for (int j2 = 0; j2 < TH_/2; ++j2) {
            const float2* s = &sv[j2][x];
            const float2 t0 = s[0], t1 = s[1], t2 = s[2], t3 = s[3], t4 = s[4],
                         t5 = s[5], t6 = s[6], t7 = s[7], t8 = s[8];
            const float blx = fmaf(G4T, t0.x + t8.x,
                              fmaf(G3T, t1.x + t7.x,
                              fmaf(G2T, t2.x + t6.x,
                              fmaf(G1T, t3.x + t5.x, t4.x))));
            const float bly = fmaf(G4T, t0.y + t8.y,
                              fmaf(G3T, t1.y + t7.y,
                              fmaf(G2T, t2.y + t6.y,
                              fmaf(G1T, t3.y + t5.y, t4.y))));
            const float4 iv0 = si[2*j2][x];
            const float4 iv1 = si[2*j2+1][x];
            const float d0 = fmaf(-iv0.x, tc0, fmaf(-iv0.y, tc1, fmaf(-iv0.z, tc2, iv0.w + m2v)));
            const float d1 = fmaf(-iv1.x, tc0, fmaf(-iv1.y, tc1, fmaf(-iv1.z, tc2, iv1.w + m2v)));
            const float u0 = __expf(-d0 * d0) * blx;   // SIGMA_2 = 1
            const float u1 = __expf(-d1 * d1) * bly;
            den += u0 + u1;
            num = fmaf(L[2*j2+4], u0, fmaf(L[2*j2+5], u1, num));
        }
        // ---- 5. wave reduce; rb double-buffered by kk&1 (no extra barrier) --
        for (int o = 32; o > 0; o >>= 1) { num += __shfl_down(num, o); den += __shfl_down(den, o); }
        if (lane == 0) { rb[kk & 1][widx][0] = num; rb[kk & 1][widx][1] = den; }
        // ---- 6. RAW barrier (lgkm drain makes rb visible; sv reads done) ----
        asm volatile("s_waitcnt lgkmcnt(0)" ::: "memory");
        __builtin_amdgcn_s_barrier();
        asm volatile("" ::: "memory");
        // ---- 7. per-k block partial ----
        if (x == 0) {
            const int p = kk & 1;
            const float fn = rb[p][0][0] + rb[p][1][0] + rb[p][2][0] + rb[p][3][0];
            const float fd = rb[p][0][1] + rb[p][1][1] + rb[p][2][1] + rb[p][3][1];
            atomicAdd(&ws[WS_ND_ + 2*(k0g + kk)],     fn);
            atomicAdd(&ws[WS_ND_ + 2*(k0g + kk) + 1], fd);
        }
        // ---- 8. rotate labels (first use of step-1 loads: counted vmcnt) ----
        if (kk < KT_ - 1) {
#pragma unroll
            for (int i = 0; i < 16; ++i) L[i] = NL[i];
            lb += HW_;
        }
    }

    // ---- completion counter + finalize in last block ----
    __syncthreads();
    if (x == 0) {
        __threadfence();
        sdone = atomicAdd((unsigned*)(ws + WS_CNT_), 1u);
    }
    __syncthreads();
    if (sdone == (unsigned)(NBLK_FUSED_ - 1)) {
        __threadfence();
        if (x < 64) {
            float term = 0.f;
            if (x < K_) {
                const float ns = ws[WS_ND_ + 2*x];
                const float ds = ws[WS_ND_ + 2*x + 1];
                term = fabsf(ns / (ds + 1e-6f));
            }
            for (int o = 32; o > 0; o >>= 1) term += __shfl_down(term, o);
            if (x == 0) out[0] = (float)K_ - term;
        }
    }
}

extern "C" void kernel_launch(void* const* d_in, const int* in_sizes, int n_in,
                              void* d_out, int out_size, void* d_ws, size_t ws_size,
                              hipStream_t stream) {
    const float* labels = (const float*)d_in[0];
    const float* inputs = (const float*)d_in[1];
    float* ws = (float*)d_ws;   // needs WS_CNT_+1 floats ~= 82 KB

    stats_k<<<dim3(SCH_, K_ / KT_, B_), 256, 0, stream>>>(labels, inputs, ws);
    fused_k<<<NBLK_FUSED_, 256, 0, stream>>>(labels, inputs, ws, (float*)d_out);
}

// Round 13
// 200.517 us; speedup vs baseline: 1.4398x; 1.4398x over previous
//
#include <hip/hip_runtime.h>

#define B_ 16
#define K_ 20
#define H_ 256
#define W_ 256
#define HW_ (H_*W_)
#define BK_ (B_*K_)
#define TH_ 64          // rows per strip (4 strips/image)
#define BATCH_ 8        // rows per barrier phase
#define KT_ 10          // stats: classes per block
#define SCH_ 16         // stats: row-chunks (16 rows each) -> 512 blocks
#define NBLK_FUSED_ 640 // 16 b x 10 k-pairs x 4 strips

// ws layout (floats): statsP [SCH_][4][BK_] | ndP [K_][64][2] | cnt
#define WS_ND_   (SCH_*4*BK_)        // 20480
#define WS_CNT_  (WS_ND_ + 2*K_*64)  // +2560

// Gaussian taps exp(-d^2/50), d=1..4 (symmetric: 4 distinct + center 1.0)
#define G1T 0.980198673f
#define G2T 0.923116346f
#define G3T 0.835270211f
#define G4T 0.726149037f

__device__ __forceinline__ float rfl(float v) {   // force value into SGPR
    return __int_as_float(__builtin_amdgcn_readfirstlane(__float_as_int(v)));
}

// ---------------------------------------------------------------------------
// stats_k: per-(b,k) sums as per-chunk partials (KT=10, validated R11).
// Also resets the fused completion counter.
// ---------------------------------------------------------------------------
__global__ __launch_bounds__(256) void stats_k(const float* __restrict__ labels,
                                               const float* __restrict__ inputs,
                                               float* __restrict__ ws) {
    const int x = threadIdx.x;
    const int chunk = blockIdx.x;
    const int kt = blockIdx.y;          // 0..1
    const int b  = blockIdx.z;
    const int k0 = kt * KT_;
    if (chunk == 0 && kt == 0 && b == 0 && x == 0)
        ((unsigned*)(ws + WS_CNT_))[0] = 0u;

    const int cbase = chunk * (16 * W_ / 4);
    const float4* in0 = (const float4*)inputs + (size_t)b * 3 * (HW_/4) + cbase;
    const float4* in1 = in0 + (HW_/4);
    const float4* in2 = in1 + (HW_/4);
    const float4* lb  = (const float4*)labels + (size_t)(b * K_ + k0) * (HW_/4) + cbase;

    float acc[KT_][4];
#pragma unroll
    for (int kk = 0; kk < KT_; ++kk)
        acc[kk][0] = acc[kk][1] = acc[kk][2] = acc[kk][3] = 0.f;

#pragma unroll
    for (int it = 0; it < 4; ++it) {
        const int idx = it * 256 + x;
        const float4 a0 = in0[idx];
        const float4 a1 = in1[idx];
        const float4 a2 = in2[idx];
#pragma unroll
        for (int kk = 0; kk < KT_; ++kk) {
            const float4 l = lb[kk * (HW_/4) + idx];
            acc[kk][0] += (l.x + l.y) + (l.z + l.w);
            acc[kk][1] += fmaf(l.w, a0.w, fmaf(l.z, a0.z, fmaf(l.y, a0.y, l.x * a0.x)));
            acc[kk][2] += fmaf(l.w, a1.w, fmaf(l.z, a1.z, fmaf(l.y, a1.y, l.x * a1.x)));
            acc[kk][3] += fmaf(l.w, a2.w, fmaf(l.z, a2.z, fmaf(l.y, a2.y, l.x * a2.w)));
        }
    }

#pragma unroll
    for (int kk = 0; kk < KT_; ++kk)
#pragma unroll
        for (int q = 0; q < 4; ++q)
            for (int o = 32; o > 0; o >>= 1)
                acc[kk][q] += __shfl_down(acc[kk][q], o);

    __shared__ float sred[4][KT_][4];
    const int widx = x >> 6, lane = x & 63;
    if (lane == 0)
#pragma unroll
        for (int kk = 0; kk < KT_; ++kk)
#pragma unroll
            for (int q = 0; q < 4; ++q) sred[widx][kk][q] = acc[kk][q];
    __syncthreads();
    if (x < KT_ * 4) {
        const int kk = x >> 2, q = x & 3;
        const float v = sred[0][kk][q] + sred[1][kk][q] + sred[2][kk][q] + sred[3][kk][q];
        ws[(chunk * 4 + q) * BK_ + b * K_ + k0 + kk] = v;
    }
}

// ---------------------------------------------------------------------------
// fused_k: R11 body, but 512-THREAD BLOCKS = two 256-thread halves working
// the SAME row strip for a k-PAIR (waves 0-3 -> class 2p, waves 4-7 -> class
// 2p+1). The halves are barrier-locked in step and issue IDENTICAL input
// addresses -> the second half's input reads hit the CU's L1 (strip working
// set 24 KB < 32 KB L1). Halves the dominant per-CU L1-miss stream with ZERO
// extra registers/barriers/atomics (per-thread body identical to R11).
//   num = sum (l*w)*blur(l),  den = sum w*blur(l)   (adjoint, G symmetric)
// Float2 row-pair LDS (R11), raw s_barrier lgkm-only drain (R8), prefetch
// survives barriers (counted vmcnt at first use).
// grid: 640 blocks 1D, bijective XCD-chunk swizzle (640 % 8 == 0).
// ---------------------------------------------------------------------------
#define CAT(m) (((m) < 8) ? ring[(m)&7] : PL[(m)&7])

__global__ __launch_bounds__(512) void fused_k(const float* __restrict__ labels,
                                               const float* __restrict__ inputs,
                                               float* __restrict__ ws,
                                               float* __restrict__ out) {
    const int x    = threadIdx.x;
    const int col  = x & 255;             // column
    const int half = x >> 8;              // 0..1 -> class within pair
    const int wave = x >> 6;              // 0..7
    const int lane = x & 63;
    const int bid = blockIdx.x;
    const int swz = (bid & 7) * (NBLK_FUSED_ / 8) + (bid >> 3);
    const int b   = swz / 40;
    const int rem = swz - b * 40;
    const int kp  = rem >> 2;             // 0..9
    const int sg  = rem & 3;              // 0..3
    const int k   = kp * 2 + half;
    const int bk  = b * K_ + k;
    const int r0  = sg * TH_;

    // ---- class mean from stats partials (uniform per wave -> SGPRs) ----
    float s0 = 0.f, s1 = 0.f, s2 = 0.f, s3 = 0.f;
#pragma unroll
    for (int c = 0; c < SCH_; ++c) {
        const float* p = ws + c * 4 * BK_;
        s0 += p[bk]; s1 += p[BK_ + bk]; s2 += p[2*BK_ + bk]; s3 += p[3*BK_ + bk];
    }
    const float dnv = s0 + 1e-5f * (float)HW_;
    const float c0 = s1 / dnv, c1 = s2 / dnv, c2 = s3 / dnv;
    const float tc0 = rfl(2.f * c0), tc1 = rfl(2.f * c1), tc2 = rfl(2.f * c2);
    const float m2v = rfl(c0*c0 + c1*c1 + c2*c2);

    const float* lb  = labels + (size_t)bk * HW_;
    const float* i0p = inputs + (size_t)b * 3 * HW_;
    const float* i1p = i0p + HW_;
    const float* i2p = i1p + HW_;

    // [half][buf][row-pair][col]: rows (2j2,2j2+1) packed as float2 (33.8 KB)
    __shared__ float2 sv[2][2][BATCH_/2][W_ + 8];
    if (x < 128) {                        // 2 half x 2 buf x 4 pairs x 8 pads
        const int hh = x >> 6, bu = (x >> 5) & 1, j2 = (x >> 3) & 3, p = x & 7;
        const int cpad = (p < 4) ? p : (W_ + p);
        sv[hh][bu][j2][cpad] = make_float2(0.f, 0.f);
    }

    // ---- prologue state (identical to R11 per-thread) ----
    float ring[8], PL[8], PW[8];
#pragma unroll
    for (int i = 0; i < 8; ++i) {
        const int gr = r0 - 4 + i;
        ring[i] = (gr >= 0) ? lb[gr * W_ + col] : 0.f;
    }
#pragma unroll
    for (int i = 0; i < 8; ++i)
        PL[i] = lb[(r0 + 4 + i) * W_ + col];
#pragma unroll
    for (int i = 0; i < 8; ++i) {
        const int r = r0 + i;
        const float a0 = i0p[r * W_ + col], a1 = i1p[r * W_ + col], a2 = i2p[r * W_ + col];
        const float d = fmaf(a0, a0 - tc0, fmaf(a1, a1 - tc1, fmaf(a2, a2 - tc2, m2v)));
        PW[i] = __expf(-d * d);           // SIGMA_2 = 1
    }
    __syncthreads();                      // pads visible (full sync, once)

    float num = 0.f, den = 0.f;
#pragma unroll 1
    for (int bt = 0; bt < TH_ / BATCH_; ++bt) {
        const int R = r0 + bt * BATCH_;
        const int bf = bt & 1;
        // ---- 1. issue next-batch loads (survive the raw barrier) ----
        float NL[8];
#pragma unroll
        for (int i = 0; i < 8; ++i) {
            const int gr = R + 12 + i;
            NL[i] = (gr < H_) ? lb[gr * W_ + col] : 0.f;
        }
        float a0v[8], a1v[8], a2v[8];
#pragma unroll
        for (int i = 0; i < 8; ++i) {
            int r = R + 8 + i; r = (r < H_) ? r : H_ - 1;
            a0v[i] = i0p[r * W_ + col]; a1v[i] = i1p[r * W_ + col]; a2v[i] = i2p[r * W_ + col];
        }
        // ---- 2. vertical 9-tap, row pairs -> LDS ----
#pragma unroll
        for (int j2 = 0; j2 < 4; ++j2) {
            const int j = 2 * j2;
            const float v0 = fmaf(G4T, CAT(j) + CAT(j+8),
                             fmaf(G3T, CAT(j+1) + CAT(j+7),
                             fmaf(G2T, CAT(j+2) + CAT(j+6),
                             fmaf(G1T, CAT(j+3) + CAT(j+5), CAT(j+4)))));
            const float v1 = fmaf(G4T, CAT(j+1) + CAT(j+9),
                             fmaf(G3T, CAT(j+2) + CAT(j+8),
                             fmaf(G2T, CAT(j+3) + CAT(j+7),
                             fmaf(G1T, CAT(j+4) + CAT(j+6), CAT(j+5)))));
            sv[half][bf][j2][4 + col] = make_float2(v0, v1);
        }
        // ---- 3. RAW barrier: drain LDS only; global loads stay in flight ----
        asm volatile("s_waitcnt lgkmcnt(0)" ::: "memory");
        __builtin_amdgcn_s_barrier();
        asm volatile("" ::: "memory");
        // ---- 4. h-blur + combine, two rows per pass ----
#pragma unroll
        for (int j2 = 0; j2 < 4; ++j2) {
            const int j = 2 * j2;
            const float2* s = &sv[half][bf][j2][col];
            const float2 t0 = s[0], t1 = s[1], t2 = s[2], t3 = s[3], t4 = s[4],
                         t5 = s[5], t6 = s[6], t7 = s[7], t8 = s[8];
            const float blx = fmaf(G4T, t0.x + t8.x,
                              fmaf(G3T, t1.x + t7.x,
                              fmaf(G2T, t2.x + t6.x,
                              fmaf(G1T, t3.x + t5.x, t4.x))));
            const float bly = fmaf(G4T, t0.y + t8.y,
                              fmaf(G3T, t1.y + t7.y,
                              fmaf(G2T, t2.y + t6.y,
                              fmaf(G1T, t3.y + t5.y, t4.y))));
            const float u0 = PW[j]   * blx;
            const float u1 = PW[j+1] * bly;
            den += u0 + u1;
            num = fmaf(CAT(j+4), u0, fmaf(CAT(j+5), u1, num));
        }
        // ---- 5. next weights + rotate state (first use of step-1 loads) ----
#pragma unroll
        for (int i = 0; i < 8; ++i) {
            const float d = fmaf(a0v[i], a0v[i] - tc0,
                            fmaf(a1v[i], a1v[i] - tc1,
                            fmaf(a2v[i], a2v[i] - tc2, m2v)));
            const float w = __expf(-d * d);
            ring[i] = PL[i]; PL[i] = NL[i]; PW[i] = w;
        }
    }

    // ---- block reduce (per half) + last-block finalize ----
    for (int o = 32; o > 0; o >>= 1) { num += __shfl_down(num, o); den += __shfl_down(den, o); }
    __shared__ float rb[8][2];
    __shared__ unsigned sdone;
    __syncthreads();
    if (lane == 0) { rb[wave][0] = num; rb[wave][1] = den; }
    __syncthreads();
    if (lane == 0 && (wave & 3) == 0) {   // x==0 (half 0) and x==256 (half 1)
        const int w0 = half * 4;
        const float fn = rb[w0][0] + rb[w0+1][0] + rb[w0+2][0] + rb[w0+3][0];
        const float fd = rb[w0][1] + rb[w0+1][1] + rb[w0+2][1] + rb[w0+3][1];
        float2* nd2 = (float2*)(ws + WS_ND_);
        nd2[k * 64 + b * 4 + sg] = make_float2(fn, fd);
        __threadfence();                  // each writer fences its own store
    }
    __syncthreads();
    if (x == 0) sdone = atomicAdd((unsigned*)(ws + WS_CNT_), 1u);
    __syncthreads();
    if (sdone == (unsigned)(NBLK_FUSED_ - 1)) {
        __threadfence();
        if (x < 64) {
            float term = 0.f;
            if (x < K_) {
                const float2* nd2 = (const float2*)(ws + WS_ND_);
                float ns = 0.f, ds = 0.f;
                for (int i = 0; i < 64; ++i) {
                    const float2 v = nd2[x * 64 + i];
                    ns += v.x; ds += v.y;
                }
                term = fabsf(ns / (ds + 1e-6f));
            }
            for (int o = 32; o > 0; o >>= 1) term += __shfl_down(term, o);
            if (x == 0) out[0] = (float)K_ - term;
        }
    }
}

extern "C" void kernel_launch(void* const* d_in, const int* in_sizes, int n_in,
                              void* d_out, int out_size, void* d_ws, size_t ws_size,
                              hipStream_t stream) {
    const float* labels = (const float*)d_in[0];
    const float* inputs = (const float*)d_in[1];
    float* ws = (float*)d_ws;   // needs WS_CNT_+1 floats ~= 92 KB

    stats_k<<<dim3(SCH_, K_ / KT_, B_), 256, 0, stream>>>(labels, inputs, ws);
    fused_k<<<NBLK_FUSED_, 512, 0, stream>>>(labels, inputs, ws, (float*)d_out);
}